// Round 3
// baseline (805.042 us; speedup 1.0000x reference)
//
#include <hip/hip_runtime.h>
#include <stdint.h>

typedef unsigned short u16;
typedef unsigned int u32;
typedef __attribute__((ext_vector_type(8))) u16 u16x8;
typedef __attribute__((ext_vector_type(8))) __bf16 bf16x8;
typedef __attribute__((ext_vector_type(4))) float f32x4;

__device__ __forceinline__ float bf2f(u16 u){
  u32 x = ((u32)u) << 16;
  return __builtin_bit_cast(float, x);
}
__device__ __forceinline__ u16 f2bf(float f){
  u32 u = __builtin_bit_cast(u32, f);
  u += 0x7FFF + ((u >> 16) & 1);   // RTNE, inputs finite
  return (u16)(u >> 16);
}
__device__ __forceinline__ f32x4 mfma16(u16x8 a, u16x8 b, f32x4 c){
  return __builtin_amdgcn_mfma_f32_16x16x32_bf16(
      __builtin_bit_cast(bf16x8, a), __builtin_bit_cast(bf16x8, b), c, 0, 0, 0);
}

// ---------------------------------------------------------------------------
// Transpose+cast fp32 W[K=2048][N] -> bf16 out[N][2048] (N-major for MFMA B)
// grid (N/64, 32), block 256
__global__ __launch_bounds__(256) void tcast_kernel(const float* __restrict__ W,
                                                    u16* __restrict__ out, int N){
  __shared__ u16 t[64][65];
  int n0 = blockIdx.x * 64, k0 = blockIdx.y * 64;
  int tid = threadIdx.x;
#pragma unroll
  for (int i = 0; i < 16; i++){
    int idx = i*256 + tid;
    int r = idx >> 6, c = idx & 63;                   // r: k, c: n
    t[r][c] = f2bf(W[(size_t)(k0 + r) * N + n0 + c]);
  }
  __syncthreads();
#pragma unroll
  for (int i = 0; i < 16; i++){
    int idx = i*256 + tid;
    int rn = idx >> 6, ck = idx & 63;                 // rn: n, ck: k
    out[(size_t)(n0 + rn) * 2048 + k0 + ck] = t[ck][rn];
  }
}

// ---------------------------------------------------------------------------
// mod = silu(temb) @ w_mod + b_mod  (split-K partials)
// grid (24, 16), block 256 ; part[(dc*2+b)*6144 + col]
__global__ __launch_bounds__(256) void mod_part_kernel(const float* __restrict__ temb,
                                                       const float* __restrict__ w_mod,
                                                       float* __restrict__ part){
  __shared__ float sl[2][128];
  int tid = threadIdx.x;
  int dc = blockIdx.y;
  if (tid < 128){ float x = temb[dc*128 + tid];        sl[0][tid]     = x / (1.0f + __expf(-x)); }
  else          { float x = temb[2048 + dc*128 + tid-128]; sl[1][tid-128] = x / (1.0f + __expf(-x)); }
  __syncthreads();
  int col = blockIdx.x * 256 + tid;
  float a0 = 0.f, a1 = 0.f;
  for (int d = 0; d < 128; d++){
    float w = w_mod[(size_t)(dc*128 + d) * 6144 + col];
    a0 += sl[0][d] * w; a1 += sl[1][d] * w;
  }
  part[(size_t)(dc*2 + 0)*6144 + col] = a0;
  part[(size_t)(dc*2 + 1)*6144 + col] = a1;
}
// grid 24, block 256
__global__ __launch_bounds__(256) void mod_reduce_kernel(const float* __restrict__ part,
                                                         const float* __restrict__ b_mod,
                                                         float* __restrict__ mod){
  int col = blockIdx.x * 256 + threadIdx.x;
  float a0 = b_mod[col], a1 = b_mod[col];
  for (int c = 0; c < 16; c++){
    a0 += part[(size_t)(c*2 + 0)*6144 + col];
    a1 += part[(size_t)(c*2 + 1)*6144 + col];
  }
  mod[col] = a0;
  mod[6144 + col] = a1;
}

// ---------------------------------------------------------------------------
// xm = (rmsnorm(hidden)*w_ln)*(1+scale)+shift  -> bf16 [4096][2048]
// grid 4096, block 256
__global__ __launch_bounds__(256) void rmsmod_kernel(const float* __restrict__ hid,
                                                     const float* __restrict__ w_ln,
                                                     const float* __restrict__ mod,
                                                     u16* __restrict__ xm){
  int token = blockIdx.x; int b = token >> 11;
  const float* row = hid + (size_t)token * 2048;
  int tid = threadIdx.x;
  float4 v0 = reinterpret_cast<const float4*>(row)[tid*2];
  float4 v1 = reinterpret_cast<const float4*>(row)[tid*2 + 1];
  float ss = v0.x*v0.x + v0.y*v0.y + v0.z*v0.z + v0.w*v0.w
           + v1.x*v1.x + v1.y*v1.y + v1.z*v1.z + v1.w*v1.w;
#pragma unroll
  for (int d = 1; d < 64; d <<= 1) ss += __shfl_xor(ss, d);
  __shared__ float red[4];
  int w = tid >> 6, lane = tid & 63;
  if (lane == 0) red[w] = ss;
  __syncthreads();
  float tot = red[0] + red[1] + red[2] + red[3];
  float inv = rsqrtf(tot * (1.0f/2048.0f) + 1e-5f);
  int c0 = tid * 8;
  const float* sh = mod + (size_t)b * 6144;
  const float* sc = sh + 2048;
  float vals[8] = {v0.x,v0.y,v0.z,v0.w,v1.x,v1.y,v1.z,v1.w};
  u16x8 o;
#pragma unroll
  for (int j = 0; j < 8; j++){
    int c = c0 + j;
    float x = vals[j] * inv * w_ln[c];
    x = x * (1.0f + sc[c]) + sh[c];
    o[j] = f2bf(x);
  }
  *reinterpret_cast<u16x8*>(xm + (size_t)token*2048 + c0) = o;
}

// ---------------------------------------------------------------------------
// bf16 GEMM: C[M][N] = A[M][K] @ Bt[N][K]^T ; 128x128 tile, 4 waves, BK=32
// EPI 0: C -> bf16 Cbf ; EPI 1: Cf = hid + gate*acc (fp32), N==2048
template<int EPI>
__global__ __launch_bounds__(256) void gemm_kernel(const u16* __restrict__ A,
                                                   const u16* __restrict__ Bt,
                                                   int M, int N, int K,
                                                   u16* __restrict__ Cbf,
                                                   const float* __restrict__ hid,
                                                   const float* __restrict__ mod,
                                                   float* __restrict__ Cf){
  __shared__ __attribute__((aligned(16))) u16 Al[128*32];
  __shared__ __attribute__((aligned(16))) u16 Bl[128*32];
  int tid = threadIdx.x, w = tid >> 6, lane = tid & 63, g = lane >> 4, r16 = lane & 15;
  int m0 = blockIdx.y * 128, n0 = blockIdx.x * 128;
  const f32x4 fz = {0.f,0.f,0.f,0.f};
  f32x4 acc[4][4];
#pragma unroll
  for (int mt = 0; mt < 4; mt++)
#pragma unroll
    for (int nt = 0; nt < 4; nt++) acc[mt][nt] = fz;

  for (int kt = 0; kt < K; kt += 32){
#pragma unroll
    for (int i = 0; i < 2; i++){
      int c = i*256 + tid;
      int row = c >> 2, slot = c & 3;
      int wpos = row*64 + ((slot*16) ^ ((row & 3) << 4));
      u16x8 va = *reinterpret_cast<const u16x8*>(A  + (size_t)(m0+row)*K + kt + slot*8);
      *reinterpret_cast<u16x8*>((char*)Al + wpos) = va;
      u16x8 vb = *reinterpret_cast<const u16x8*>(Bt + (size_t)(n0+row)*K + kt + slot*8);
      *reinterpret_cast<u16x8*>((char*)Bl + wpos) = vb;
    }
    __syncthreads();
    u16x8 af[4], bfr[4];
    int mbase = (w >> 1) * 64, nbase = (w & 1) * 64;
#pragma unroll
    for (int mt = 0; mt < 4; mt++){
      int row = mbase + mt*16 + r16;
      af[mt] = *reinterpret_cast<const u16x8*>((char*)Al + row*64 + ((g*16) ^ ((row & 3) << 4)));
    }
#pragma unroll
    for (int nt = 0; nt < 4; nt++){
      int row = nbase + nt*16 + r16;
      bfr[nt] = *reinterpret_cast<const u16x8*>((char*)Bl + row*64 + ((g*16) ^ ((row & 3) << 4)));
    }
#pragma unroll
    for (int mt = 0; mt < 4; mt++)
#pragma unroll
      for (int nt = 0; nt < 4; nt++)
        acc[mt][nt] = mfma16(af[mt], bfr[nt], acc[mt][nt]);
    __syncthreads();
  }
  int mbase = m0 + (w >> 1)*64, nbase = n0 + (w & 1)*64;
#pragma unroll
  for (int mt = 0; mt < 4; mt++){
#pragma unroll
    for (int nt = 0; nt < 4; nt++){
#pragma unroll
      for (int r = 0; r < 4; r++){
        int m = mbase + mt*16 + g*4 + r;
        int n = nbase + nt*16 + r16;
        float v = acc[mt][nt][r];
        if constexpr (EPI == 0){
          Cbf[(size_t)m*N + n] = f2bf(v);
        } else {
          int b = m >> 11;
          float gate = mod[(size_t)b*6144 + 4096 + n];
          Cf[(size_t)m*N + n] = hid[(size_t)m*N + n] + gate * v;
        }
      }
    }
  }
}

// ---------------------------------------------------------------------------
// Per-(token, head) QK RMSNorm + mixed RoPE, V pass-through. 1 wave per head.
// grid (4096, 8), block 256. head = blockIdx.y*4+wave: 0-15 q, 16-23 k, 24-31 v
// mpos arrives as little-endian int64 (reference declares int64); tolerate int32.
__global__ __launch_bounds__(256) void qknorm_rope_kernel(const u16* __restrict__ QKV,
                                                          const float* __restrict__ qn,
                                                          const float* __restrict__ kn,
                                                          const float* __restrict__ cos1,
                                                          const float* __restrict__ sin1,
                                                          const float* __restrict__ rope3,
                                                          const int* __restrict__ mpos,
                                                          u16* __restrict__ Qo,
                                                          u16* __restrict__ Ko,
                                                          u16* __restrict__ Vo){
  int token = blockIdx.x;
  int b = token >> 11, l = token & 2047;
  int wid = threadIdx.x >> 6, lane = threadIdx.x & 63;
  int head = blockIdx.y * 4 + wid;
  const u16* src = QKV + (size_t)token * 4096;
  if (head >= 24){                       // V: plain copy to (B,KVH,L,Dh)
    int kvh = head - 24;
    const u16* s = src + 3072 + kvh*128;
    u16* d = Vo + ((size_t)(b*8 + kvh)*2048 + l)*128;
    reinterpret_cast<u32*>(d)[lane] = reinterpret_cast<const u32*>(s)[lane];
    return;
  }
  bool isq = head < 16;
  int hh = isq ? head : head - 16;
  const u16* s = src + (isq ? hh*128 : 2048 + hh*128);
  float f0 = bf2f(s[lane]), f1 = bf2f(s[lane + 64]);
  // RMS over 128
  float ss = f0*f0 + f1*f1;
#pragma unroll
  for (int d = 1; d < 64; d <<= 1) ss += __shfl_xor(ss, d);
  float inv = rsqrtf(ss * (1.0f/128.0f) + 1e-5f);
  const float* nw = isq ? qn : kn;
  f0 *= inv * nw[lane];
  f1 *= inv * nw[lane + 64];
  // masks from modality_positions (2 segments), int32/int64 tolerant
  bool is64 = (mpos[1] == 0) & (mpos[3] == 0) & (mpos[5] == 0) & (mpos[7] == 0);
  bool in_full = false, in_img = false; int rel = 0;
#pragma unroll
  for (int sg = 0; sg < 2; sg++){
    int e = b*4 + sg*2;
    int off = is64 ? mpos[2*e]       : mpos[e];
    int ln  = is64 ? mpos[2*e + 2]   : mpos[e + 1];
    int mx = ln > 1 ? ln : 1;
    in_full = in_full || (l >= off && l < off + mx);
    bool ii = (l >= off + 1 && l < off + ln);
    in_img = in_img || ii;
    if (ii) rel += l - (off + 1);
  }
  bool txt = !in_full;
  bool img = in_img && rel >= 0 && rel < 1024;
  int relc = rel < 0 ? 0 : (rel > 1023 ? 1023 : rel);
  float o0, o1;
  if (txt){
    float c0 = cos1[(size_t)l*128 + lane],      s0 = sin1[(size_t)l*128 + lane];
    float c1 = cos1[(size_t)l*128 + lane + 64], s1 = sin1[(size_t)l*128 + lane + 64];
    o0 = f0*c0 - f1*s0;          // rotate_half: first half gets -x2*s
    o1 = f1*c1 + f0*s1;
  } else {
    float m0 = __shfl_xor(f0, 1), m1 = __shfl_xor(f1, 1);
    if (img){
      int p0 = lane >> 1, p1 = 32 + (lane >> 1);
      const float* R0 = rope3 + ((size_t)relc*64 + p0)*4;
      const float* R1 = rope3 + ((size_t)relc*64 + p1)*4;
      if ((lane & 1) == 0){ o0 = f0*R0[0] + m0*R0[2]; o1 = f1*R1[0] + m1*R1[2]; }
      else                { o0 = m0*R0[1] + f0*R0[3]; o1 = m1*R1[1] + f1*R1[3]; }
    } else { o0 = f0; o1 = f1; }
  }
  u16* dst = isq ? (Qo + ((size_t)(b*16 + hh)*2048 + l)*128)
                 : (Ko + ((size_t)(b*8  + hh)*2048 + l)*128);
  dst[lane]      = f2bf(o0);
  dst[lane + 64] = f2bf(o1);
}

// ---------------------------------------------------------------------------
// Flash attention: grid (32, 32) = (L/64, B*H); block 256 (4 waves x 16 q-rows)
// K LDS swizzled row-major; V transposed in LDS; P via padded per-wave LDS.
__global__ __launch_bounds__(256) void attn_kernel(const u16* __restrict__ Q,
                                                   const u16* __restrict__ K,
                                                   const u16* __restrict__ V,
                                                   u16* __restrict__ O){
  __shared__ __attribute__((aligned(16))) u16 Kl[64*128];
  __shared__ __attribute__((aligned(16))) u16 Vt[128*72];   // [d][kv], pad 72
  __shared__ __attribute__((aligned(16))) u16 Pl[4][16*72]; // per-wave [qr][kv], pad 72
  int tid = threadIdx.x, w = tid >> 6, lane = tid & 63, g = lane >> 4, r16 = lane & 15;
  int bh = blockIdx.y, b = bh >> 4, h = bh & 15, kvh = h >> 1;
  int q0 = blockIdx.x * 64 + w * 16;
  const u16* Qb = Q + ((size_t)((b*16 + h)*2048) + q0) * 128;
  const u16* Kb = K + ((size_t)((b*8 + kvh)*2048)) * 128;
  const u16* Vb = V + ((size_t)((b*8 + kvh)*2048)) * 128;
  u16x8 qf[4];
#pragma unroll
  for (int kk = 0; kk < 4; kk++)
    qf[kk] = *reinterpret_cast<const u16x8*>(Qb + r16*128 + kk*32 + g*8);
  const f32x4 fz = {0.f,0.f,0.f,0.f};
  f32x4 accO[8];
#pragma unroll
  for (int i = 0; i < 8; i++) accO[i] = fz;
  float mrow[4] = {-1e30f,-1e30f,-1e30f,-1e30f};
  float lrow[4] = {0.f,0.f,0.f,0.f};
  const float scale = 0.08838834764831845f;
  u16* Pw = Pl[w];

  for (int kv0 = 0; kv0 < 2048; kv0 += 64){
#pragma unroll
    for (int i = 0; i < 4; i++){
      int c = i*256 + tid;
      int row = c >> 4, ch = c & 15;
      u16x8 kvv = *reinterpret_cast<const u16x8*>(Kb + (size_t)(kv0+row)*128 + ch*8);
      *reinterpret_cast<u16x8*>((char*)Kl + row*256 + ((ch*16) ^ ((row & 7) << 4))) = kvv;
      u16x8 vv = *reinterpret_cast<const u16x8*>(Vb + (size_t)(kv0+row)*128 + ch*8);
#pragma unroll
      for (int j = 0; j < 8; j++)                 // transpose scatter (fix: tr_b16 later)
        Vt[(ch*8 + j)*72 + row] = vv[j];
    }
    __syncthreads();
    // S = Q K^T (per-wave 16x64)
    f32x4 s[4];
#pragma unroll
    for (int nt = 0; nt < 4; nt++){
      s[nt] = fz;
      int row = nt*16 + r16;
      int swz = (row & 7) << 4;
#pragma unroll
      for (int kk = 0; kk < 4; kk++){
        u16x8 kf = *reinterpret_cast<const u16x8*>((char*)Kl + row*256 + ((kk*64 + g*16) ^ swz));
        s[nt] = mfma16(qf[kk], kf, s[nt]);
      }
    }
    // online softmax (rows = g*4+r, cols across 16 lanes + 4 ntiles)
    float alpha[4];
#pragma unroll
    for (int r = 0; r < 4; r++){
#pragma unroll
      for (int nt = 0; nt < 4; nt++) s[nt][r] *= scale;
      float pm = fmaxf(fmaxf(s[0][r], s[1][r]), fmaxf(s[2][r], s[3][r]));
#pragma unroll
      for (int d = 1; d < 16; d <<= 1) pm = fmaxf(pm, __shfl_xor(pm, d));
      float mnew = fmaxf(mrow[r], pm);
      alpha[r] = __expf(mrow[r] - mnew);
      float rs = 0.f;
#pragma unroll
      for (int nt = 0; nt < 4; nt++){
        float p = __expf(s[nt][r] - mnew);
        s[nt][r] = p;
        rs += p;
      }
#pragma unroll
      for (int d = 1; d < 16; d <<= 1) rs += __shfl_xor(rs, d);
      lrow[r] = lrow[r]*alpha[r] + rs;
      mrow[r] = mnew;
    }
#pragma unroll
    for (int nt = 0; nt < 8; nt++)
#pragma unroll
      for (int r = 0; r < 4; r++) accO[nt][r] *= alpha[r];
    // P -> LDS (bf16)
#pragma unroll
    for (int nt = 0; nt < 4; nt++)
#pragma unroll
      for (int r = 0; r < 4; r++)
        Pw[(g*4 + r)*72 + nt*16 + r16] = f2bf(s[nt][r]);
    // O += P @ V
#pragma unroll
    for (int nt = 0; nt < 8; nt++){
#pragma unroll
      for (int kk2 = 0; kk2 < 2; kk2++){
        u16x8 pa = *reinterpret_cast<const u16x8*>((char*)Pw + r16*144 + kk2*64 + g*16);
        u16x8 vf = *reinterpret_cast<const u16x8*>((char*)Vt + (nt*16 + r16)*144 + kk2*64 + g*16);
        accO[nt] = mfma16(pa, vf, accO[nt]);
      }
    }
    __syncthreads();
  }
  float invl[4];
#pragma unroll
  for (int r = 0; r < 4; r++) invl[r] = 1.0f / lrow[r];
#pragma unroll
  for (int nt = 0; nt < 8; nt++){
#pragma unroll
    for (int r = 0; r < 4; r++){
      int token = q0 + g*4 + r;
      O[((size_t)(b*2048 + token))*2048 + h*128 + nt*16 + r16] = f2bf(accO[nt][r] * invl[r]);
    }
  }
}

// ---------------------------------------------------------------------------
extern "C" void kernel_launch(void* const* d_in, const int* in_sizes, int n_in,
                              void* d_out, int out_size, void* d_ws, size_t ws_size,
                              hipStream_t stream){
  (void)in_sizes; (void)n_in; (void)out_size; (void)ws_size;
  const float* hid   = (const float*)d_in[0];
  const float* temb  = (const float*)d_in[1];
  const float* w_ln  = (const float*)d_in[2];
  const float* w_mod = (const float*)d_in[3];
  const float* b_mod = (const float*)d_in[4];
  const float* wq    = (const float*)d_in[5];
  const float* wk    = (const float*)d_in[6];
  const float* wv    = (const float*)d_in[7];
  const float* wo    = (const float*)d_in[8];
  const float* qn_w  = (const float*)d_in[9];
  const float* kn_w  = (const float*)d_in[10];
  const float* cos1  = (const float*)d_in[11];
  const float* sin1  = (const float*)d_in[12];
  const float* rope3 = (const float*)d_in[13];
  const int*   mpos  = (const int*)d_in[14];
  float* out = (float*)d_out;

  // Workspace map (sizes in MB, all regions verified non-overlapping for
  // their live ranges):
  //   [0, 48K)      modb   (2*6144 fp32 = 48 KB)
  //   [128K, 896K)  partb  (32*6144 fp32 = 768 KB)
  //   [1, 17)       xm     4096x2048 bf16 = 16 MB ; DEAD after gemm<0>;
  //                        reused as ao (attn output, 16 MB)
  //   [17, 33)      wqkvT  4096x2048 bf16 = 16 MB ; DEAD after gemm<0>;
  //                        reused as Qn (2,16,2048,128) bf16 = 16 MB
  //   [33, 41)      woT    2048x2048 bf16 = 8 MB  (live until gemm<1>)
  //   [41, 73)      qkv    4096x4096 bf16 = 32 MB (was the round-1/2 bug:
  //                        declared 16 MB, overlapped Qn at 57 MB -> race)
  //   [73, 81)      Kn     (2,8,2048,128) bf16 = 8 MB
  //   [81, 89)      Vn     8 MB
  char* ws = (char*)d_ws;
  const size_t MB = 1u << 20;
  float* modb  = (float*)(ws + 0);
  float* partb = (float*)(ws + 131072);
  u16* xm    = (u16*)(ws + 1*MB);
  u16* wqkvT = (u16*)(ws + 17*MB);
  u16* woT   = (u16*)(ws + 33*MB);
  u16* qkv   = (u16*)(ws + 41*MB);
  u16* Qn    = (u16*)(ws + 17*MB);   // aliases wqkvT (dead by then)
  u16* Kn    = (u16*)(ws + 73*MB);
  u16* Vn    = (u16*)(ws + 81*MB);
  u16* ao    = (u16*)(ws + 1*MB);    // aliases xm (dead by then)

  // weights -> bf16, transposed (N-major)
  tcast_kernel<<<dim3(32,32), 256, 0, stream>>>(wq, wqkvT, 2048);
  tcast_kernel<<<dim3(16,32), 256, 0, stream>>>(wk, wqkvT + (size_t)2048*2048, 1024);
  tcast_kernel<<<dim3(16,32), 256, 0, stream>>>(wv, wqkvT + (size_t)3072*2048, 1024);
  tcast_kernel<<<dim3(32,32), 256, 0, stream>>>(wo, woT, 2048);
  // modulation
  mod_part_kernel<<<dim3(24,16), 256, 0, stream>>>(temb, w_mod, partb);
  mod_reduce_kernel<<<24, 256, 0, stream>>>(partb, b_mod, modb);
  // norm + modulate
  rmsmod_kernel<<<4096, 256, 0, stream>>>(hid, w_ln, modb, xm);
  // QKV projection (reads xm, wqkvT; writes qkv) — after this xm/wqkvT are dead
  gemm_kernel<0><<<dim3(32,32), 256, 0, stream>>>(xm, wqkvT, 4096, 4096, 2048,
                                                  qkv, nullptr, nullptr, nullptr);
  // qk-norm + rope + head split (reads qkv; writes Qn/Kn/Vn)
  qknorm_rope_kernel<<<dim3(4096,8), 256, 0, stream>>>(qkv, qn_w, kn_w, cos1, sin1,
                                                       rope3, mpos, Qn, Kn, Vn);
  // attention (reads Qn/Kn/Vn; writes ao)
  attn_kernel<<<dim3(32,32), 256, 0, stream>>>(Qn, Kn, Vn, ao);
  // O-projection + residual + gate (fused)
  gemm_kernel<1><<<dim3(16,32), 256, 0, stream>>>(ao, woT, 4096, 2048, 2048,
                                                  nullptr, hid, modb, out);
}

// Round 5
// 558.158 us; speedup vs baseline: 1.4423x; 1.4423x over previous
//
#include <hip/hip_runtime.h>
#include <stdint.h>

typedef unsigned short u16;
typedef unsigned int u32;
typedef __attribute__((ext_vector_type(8))) u16 u16x8;
typedef __attribute__((ext_vector_type(8))) __bf16 bf16x8;
typedef __attribute__((ext_vector_type(4))) float f32x4;

__device__ __forceinline__ float bf2f(u16 u){
  u32 x = ((u32)u) << 16;
  return __builtin_bit_cast(float, x);
}
__device__ __forceinline__ u16 f2bf(float f){
  u32 u = __builtin_bit_cast(u32, f);
  u += 0x7FFF + ((u >> 16) & 1);   // RTNE, inputs finite
  return (u16)(u >> 16);
}
__device__ __forceinline__ f32x4 mfma16(u16x8 a, u16x8 b, f32x4 c){
  return __builtin_amdgcn_mfma_f32_16x16x32_bf16(
      __builtin_bit_cast(bf16x8, a), __builtin_bit_cast(bf16x8, b), c, 0, 0, 0);
}
// async global->LDS 16B: HW writes wave-uniform LDS base + lane*16 (m104).
__device__ __forceinline__ void gl_lds16(const u16* src, u16* lds_uniform_base){
  __builtin_amdgcn_global_load_lds(
      (const __attribute__((address_space(1))) u32*)src,
      (__attribute__((address_space(3))) u32*)lds_uniform_base, 16, 0, 0);
}

// ---------------------------------------------------------------------------
// Transpose+cast fp32 W[K=2048][N] -> bf16 out[N][2048] (N-major for MFMA B)
// grid (N/64, 32), block 256
__global__ __launch_bounds__(256) void tcast_kernel(const float* __restrict__ W,
                                                    u16* __restrict__ out, int N){
  __shared__ u16 t[64][65];
  int n0 = blockIdx.x * 64, k0 = blockIdx.y * 64;
  int tid = threadIdx.x;
#pragma unroll
  for (int i = 0; i < 16; i++){
    int idx = i*256 + tid;
    int r = idx >> 6, c = idx & 63;                   // r: k, c: n
    t[r][c] = f2bf(W[(size_t)(k0 + r) * N + n0 + c]);
  }
  __syncthreads();
#pragma unroll
  for (int i = 0; i < 16; i++){
    int idx = i*256 + tid;
    int rn = idx >> 6, ck = idx & 63;                 // rn: n, ck: k
    out[(size_t)(n0 + rn) * 2048 + k0 + ck] = t[ck][rn];
  }
}

// ---------------------------------------------------------------------------
// mod = silu(temb) @ w_mod + b_mod  (split-K partials)
// grid (24, 16), block 256 ; part[(dc*2+b)*6144 + col]
__global__ __launch_bounds__(256) void mod_part_kernel(const float* __restrict__ temb,
                                                       const float* __restrict__ w_mod,
                                                       float* __restrict__ part){
  __shared__ float sl[2][128];
  int tid = threadIdx.x;
  int dc = blockIdx.y;
  if (tid < 128){ float x = temb[dc*128 + tid];        sl[0][tid]     = x / (1.0f + __expf(-x)); }
  else          { float x = temb[2048 + dc*128 + tid-128]; sl[1][tid-128] = x / (1.0f + __expf(-x)); }
  __syncthreads();
  int col = blockIdx.x * 256 + tid;
  float a0 = 0.f, a1 = 0.f;
  for (int d = 0; d < 128; d++){
    float w = w_mod[(size_t)(dc*128 + d) * 6144 + col];
    a0 += sl[0][d] * w; a1 += sl[1][d] * w;
  }
  part[(size_t)(dc*2 + 0)*6144 + col] = a0;
  part[(size_t)(dc*2 + 1)*6144 + col] = a1;
}
// grid 24, block 256
__global__ __launch_bounds__(256) void mod_reduce_kernel(const float* __restrict__ part,
                                                         const float* __restrict__ b_mod,
                                                         float* __restrict__ mod){
  int col = blockIdx.x * 256 + threadIdx.x;
  float a0 = b_mod[col], a1 = b_mod[col];
  for (int c = 0; c < 16; c++){
    a0 += part[(size_t)(c*2 + 0)*6144 + col];
    a1 += part[(size_t)(c*2 + 1)*6144 + col];
  }
  mod[col] = a0;
  mod[6144 + col] = a1;
}

// ---------------------------------------------------------------------------
// xm = (rmsnorm(hidden)*w_ln)*(1+scale)+shift  -> bf16 [4096][2048]
// grid 4096, block 256
__global__ __launch_bounds__(256) void rmsmod_kernel(const float* __restrict__ hid,
                                                     const float* __restrict__ w_ln,
                                                     const float* __restrict__ mod,
                                                     u16* __restrict__ xm){
  int token = blockIdx.x; int b = token >> 11;
  const float* row = hid + (size_t)token * 2048;
  int tid = threadIdx.x;
  float4 v0 = reinterpret_cast<const float4*>(row)[tid*2];
  float4 v1 = reinterpret_cast<const float4*>(row)[tid*2 + 1];
  float ss = v0.x*v0.x + v0.y*v0.y + v0.z*v0.z + v0.w*v0.w
           + v1.x*v1.x + v1.y*v1.y + v1.z*v1.z + v1.w*v1.w;
#pragma unroll
  for (int d = 1; d < 64; d <<= 1) ss += __shfl_xor(ss, d);
  __shared__ float red[4];
  int w = tid >> 6, lane = tid & 63;
  if (lane == 0) red[w] = ss;
  __syncthreads();
  float tot = red[0] + red[1] + red[2] + red[3];
  float inv = rsqrtf(tot * (1.0f/2048.0f) + 1e-5f);
  int c0 = tid * 8;
  const float* sh = mod + (size_t)b * 6144;
  const float* sc = sh + 2048;
  float vals[8] = {v0.x,v0.y,v0.z,v0.w,v1.x,v1.y,v1.z,v1.w};
  u16x8 o;
#pragma unroll
  for (int j = 0; j < 8; j++){
    int c = c0 + j;
    float x = vals[j] * inv * w_ln[c];
    x = x * (1.0f + sc[c]) + sh[c];
    o[j] = f2bf(x);
  }
  *reinterpret_cast<u16x8*>(xm + (size_t)token*2048 + c0) = o;
}

// ---------------------------------------------------------------------------
// bf16 GEMM (m97 structure): C[M][N] = A[M][K] @ Bt[N][K]^T
// 128x128 tile, BK=64, 4 waves (2x2), global_load_lds w=16, XOR-swizzled LDS.
// Swizzle: logical byte l in a 128-B row stored at l ^ ((row&7)<<4); achieved
// with linear LDS dest + inverse-swizzled global source (involution).
// EPI 0: C -> bf16 Cbf ; EPI 1: Cf = hid + gate*acc (fp32)
template<int EPI>
__global__ __launch_bounds__(256) void gemm_kernel(const u16* __restrict__ A,
                                                   const u16* __restrict__ Bt,
                                                   int M, int N, int K,
                                                   u16* __restrict__ Cbf,
                                                   const float* __restrict__ hid,
                                                   const float* __restrict__ mod,
                                                   float* __restrict__ Cf){
  __shared__ __attribute__((aligned(16))) u16 Al[128*64];   // 16 KB
  __shared__ __attribute__((aligned(16))) u16 Bl[128*64];   // 16 KB
  int tid = threadIdx.x, w = tid >> 6, lane = tid & 63, g = lane >> 4, r16 = lane & 15;
  int m0 = blockIdx.y * 128, n0 = blockIdx.x * 128;
  const f32x4 fz = {0.f,0.f,0.f,0.f};
  f32x4 acc[4][4];
#pragma unroll
  for (int mt = 0; mt < 4; mt++)
#pragma unroll
    for (int nt = 0; nt < 4; nt++) acc[mt][nt] = fz;

  // staging coords: issue i covers LDS bytes [i*4096 + w*1024 + lane*16, +16)
  int srow = w*8 + (lane >> 3);                 // + i*32
  int scol = (lane & 7) * 16;                   // linear byte-in-row

  for (int kt = 0; kt < K; kt += 64){
#pragma unroll
    for (int i = 0; i < 4; i++){
      int row = i*32 + srow;
      int colb = scol ^ ((row & 7) << 4);       // inverse-swizzled source
      gl_lds16(A + (size_t)(m0+row)*K + kt + (colb >> 1), Al + i*2048 + w*512);
      gl_lds16(Bt + (size_t)(n0+row)*K + kt + (colb >> 1), Bl + i*2048 + w*512);
    }
    __syncthreads();                            // waits vmcnt(0)
#pragma unroll
    for (int kk = 0; kk < 2; kk++){
      u16x8 af[4], bfr[4];
#pragma unroll
      for (int mt = 0; mt < 4; mt++){
        int row = (w >> 1)*64 + mt*16 + r16;
        af[mt] = *reinterpret_cast<const u16x8*>(
            (char*)Al + row*128 + ((kk*64 + g*16) ^ ((row & 7) << 4)));
      }
#pragma unroll
      for (int nt = 0; nt < 4; nt++){
        int row = (w & 1)*64 + nt*16 + r16;
        bfr[nt] = *reinterpret_cast<const u16x8*>(
            (char*)Bl + row*128 + ((kk*64 + g*16) ^ ((row & 7) << 4)));
      }
#pragma unroll
      for (int mt = 0; mt < 4; mt++)
#pragma unroll
        for (int nt = 0; nt < 4; nt++)
          acc[mt][nt] = mfma16(af[mt], bfr[nt], acc[mt][nt]);
    }
    __syncthreads();
  }
  int mbase = m0 + (w >> 1)*64, nbase = n0 + (w & 1)*64;
#pragma unroll
  for (int mt = 0; mt < 4; mt++){
#pragma unroll
    for (int nt = 0; nt < 4; nt++){
#pragma unroll
      for (int r = 0; r < 4; r++){
        int m = mbase + mt*16 + g*4 + r;
        int n = nbase + nt*16 + r16;
        float v = acc[mt][nt][r];
        if constexpr (EPI == 0){
          Cbf[(size_t)m*N + n] = f2bf(v);
        } else {
          int b = m >> 11;
          float gate = mod[(size_t)b*6144 + 4096 + n];
          Cf[(size_t)m*N + n] = hid[(size_t)m*N + n] + gate * v;
        }
      }
    }
  }
}

// ---------------------------------------------------------------------------
// Per-(token, head) QK RMSNorm + mixed RoPE, V pass-through. 1 wave per head.
// grid (4096, 8), block 256. head = blockIdx.y*4+wave: 0-15 q, 16-23 k, 24-31 v
// mpos arrives as little-endian int64 (reference declares int64); tolerate int32.
__global__ __launch_bounds__(256) void qknorm_rope_kernel(const u16* __restrict__ QKV,
                                                          const float* __restrict__ qn,
                                                          const float* __restrict__ kn,
                                                          const float* __restrict__ cos1,
                                                          const float* __restrict__ sin1,
                                                          const float* __restrict__ rope3,
                                                          const int* __restrict__ mpos,
                                                          u16* __restrict__ Qo,
                                                          u16* __restrict__ Ko,
                                                          u16* __restrict__ Vo){
  int token = blockIdx.x;
  int b = token >> 11, l = token & 2047;
  int wid = threadIdx.x >> 6, lane = threadIdx.x & 63;
  int head = blockIdx.y * 4 + wid;
  const u16* src = QKV + (size_t)token * 4096;
  if (head >= 24){                       // V: plain copy to (B,KVH,L,Dh)
    int kvh = head - 24;
    const u16* s = src + 3072 + kvh*128;
    u16* d = Vo + ((size_t)(b*8 + kvh)*2048 + l)*128;
    reinterpret_cast<u32*>(d)[lane] = reinterpret_cast<const u32*>(s)[lane];
    return;
  }
  bool isq = head < 16;
  int hh = isq ? head : head - 16;
  const u16* s = src + (isq ? hh*128 : 2048 + hh*128);
  float f0 = bf2f(s[lane]), f1 = bf2f(s[lane + 64]);
  // RMS over 128
  float ss = f0*f0 + f1*f1;
#pragma unroll
  for (int d = 1; d < 64; d <<= 1) ss += __shfl_xor(ss, d);
  float inv = rsqrtf(ss * (1.0f/128.0f) + 1e-5f);
  const float* nw = isq ? qn : kn;
  f0 *= inv * nw[lane];
  f1 *= inv * nw[lane + 64];
  // masks from modality_positions (2 segments), int32/int64 tolerant
  bool is64 = (mpos[1] == 0) & (mpos[3] == 0) & (mpos[5] == 0) & (mpos[7] == 0);
  bool in_full = false, in_img = false; int rel = 0;
#pragma unroll
  for (int sg = 0; sg < 2; sg++){
    int e = b*4 + sg*2;
    int off = is64 ? mpos[2*e]       : mpos[e];
    int ln  = is64 ? mpos[2*e + 2]   : mpos[e + 1];
    int mx = ln > 1 ? ln : 1;
    in_full = in_full || (l >= off && l < off + mx);
    bool ii = (l >= off + 1 && l < off + ln);
    in_img = in_img || ii;
    if (ii) rel += l - (off + 1);
  }
  bool txt = !in_full;
  bool img = in_img && rel >= 0 && rel < 1024;
  int relc = rel < 0 ? 0 : (rel > 1023 ? 1023 : rel);
  float o0, o1;
  if (txt){
    float c0 = cos1[(size_t)l*128 + lane],      s0 = sin1[(size_t)l*128 + lane];
    float c1 = cos1[(size_t)l*128 + lane + 64], s1 = sin1[(size_t)l*128 + lane + 64];
    o0 = f0*c0 - f1*s0;          // rotate_half: first half gets -x2*s
    o1 = f1*c1 + f0*s1;
  } else {
    float m0 = __shfl_xor(f0, 1), m1 = __shfl_xor(f1, 1);
    if (img){
      int p0 = lane >> 1, p1 = 32 + (lane >> 1);
      const float* R0 = rope3 + ((size_t)relc*64 + p0)*4;
      const float* R1 = rope3 + ((size_t)relc*64 + p1)*4;
      if ((lane & 1) == 0){ o0 = f0*R0[0] + m0*R0[2]; o1 = f1*R1[0] + m1*R1[2]; }
      else                { o0 = m0*R0[1] + f0*R0[3]; o1 = m1*R1[1] + f1*R1[3]; }
    } else { o0 = f0; o1 = f1; }
  }
  u16* dst = isq ? (Qo + ((size_t)(b*16 + hh)*2048 + l)*128)
                 : (Ko + ((size_t)(b*8  + hh)*2048 + l)*128);
  dst[lane]      = f2bf(o0);
  dst[lane + 64] = f2bf(o1);
}

// ---------------------------------------------------------------------------
// Flash attention: grid (32, 32) = (L/64, B*H); block 256 (4 waves x 16 q-rows)
// K: global_load_lds w=16, linear dest + inverse-swz source, (row&7)<<4 swizzle.
// Vt[d][kv] [128][64]: scatter-write + read both XOR'd by ((d&7)^((d>>3)&7))<<3
// (u16 idx) -> ~4-way max on write, 2-way on read (vs 16-way before).
__global__ __launch_bounds__(256) void attn_kernel(const u16* __restrict__ Q,
                                                   const u16* __restrict__ K,
                                                   const u16* __restrict__ V,
                                                   u16* __restrict__ O){
  __shared__ __attribute__((aligned(16))) u16 Kl[64*128];   // 16 KB
  __shared__ __attribute__((aligned(16))) u16 Vt[128*64];   // 16 KB
  __shared__ __attribute__((aligned(16))) u16 Pl[4][16*72]; // 9 KB
  int tid = threadIdx.x, w = tid >> 6, lane = tid & 63, g = lane >> 4, r16 = lane & 15;
  int bh = blockIdx.y, b = bh >> 4, h = bh & 15, kvh = h >> 1;
  int q0 = blockIdx.x * 64 + w * 16;
  const u16* Qb = Q + ((size_t)((b*16 + h)*2048) + q0) * 128;
  const u16* Kb = K + ((size_t)((b*8 + kvh)*2048)) * 128;
  const u16* Vb = V + ((size_t)((b*8 + kvh)*2048)) * 128;
  u16x8 qf[4];
#pragma unroll
  for (int kk = 0; kk < 4; kk++)
    qf[kk] = *reinterpret_cast<const u16x8*>(Qb + r16*128 + kk*32 + g*8);
  const f32x4 fz = {0.f,0.f,0.f,0.f};
  f32x4 accO[8];
#pragma unroll
  for (int i = 0; i < 8; i++) accO[i] = fz;
  float mrow[4] = {-1e30f,-1e30f,-1e30f,-1e30f};
  float lrow[4] = {0.f,0.f,0.f,0.f};
  const float scale = 0.08838834764831845f;
  u16* Pw = Pl[w];
  // K staging coords (256-B rows): issue i -> rows i*16 + w*4 + (lane>>4)
  int krow_base = w*4 + (lane >> 4);
  int kcol = (lane & 15) * 16;                  // linear byte-in-row

  for (int kv0 = 0; kv0 < 2048; kv0 += 64){
    // K -> LDS async, swizzled via source
#pragma unroll
    for (int i = 0; i < 4; i++){
      int row = i*16 + krow_base;
      int colb = kcol ^ ((row & 7) << 4);
      gl_lds16(Kb + (size_t)(kv0+row)*128 + (colb >> 1), Kl + i*2048 + w*512);
    }
    // V -> LDS transposed scatter, XOR-swizzled
#pragma unroll
    for (int i = 0; i < 4; i++){
      int c = i*256 + tid;
      int row = c >> 4, ch = c & 15;
      u16x8 vv = *reinterpret_cast<const u16x8*>(Vb + (size_t)(kv0+row)*128 + ch*8);
#pragma unroll
      for (int j = 0; j < 8; j++){
        int sv = ((j ^ ch) & 7) << 3;           // = ((d&7)^((d>>3)&7))<<3, d=ch*8+j
        Vt[(ch*8 + j)*64 + (row ^ sv)] = vv[j];
      }
    }
    __syncthreads();
    // S = Q K^T (per-wave 16x64)
    f32x4 s[4];
#pragma unroll
    for (int nt = 0; nt < 4; nt++){
      s[nt] = fz;
      int row = nt*16 + r16;
      int swz = (row & 7) << 4;
#pragma unroll
      for (int kk = 0; kk < 4; kk++){
        u16x8 kf = *reinterpret_cast<const u16x8*>((char*)Kl + row*256 + ((kk*64 + g*16) ^ swz));
        s[nt] = mfma16(qf[kk], kf, s[nt]);
      }
    }
    // online softmax (rows = g*4+r, cols across 16 lanes + 4 ntiles)
    float alpha[4];
#pragma unroll
    for (int r = 0; r < 4; r++){
#pragma unroll
      for (int nt = 0; nt < 4; nt++) s[nt][r] *= scale;
      float pm = fmaxf(fmaxf(s[0][r], s[1][r]), fmaxf(s[2][r], s[3][r]));
#pragma unroll
      for (int d = 1; d < 16; d <<= 1) pm = fmaxf(pm, __shfl_xor(pm, d));
      float mnew = fmaxf(mrow[r], pm);
      alpha[r] = __expf(mrow[r] - mnew);
      float rs = 0.f;
#pragma unroll
      for (int nt = 0; nt < 4; nt++){
        float p = __expf(s[nt][r] - mnew);
        s[nt][r] = p;
        rs += p;
      }
#pragma unroll
      for (int d = 1; d < 16; d <<= 1) rs += __shfl_xor(rs, d);
      lrow[r] = lrow[r]*alpha[r] + rs;
      mrow[r] = mnew;
    }
#pragma unroll
    for (int nt = 0; nt < 8; nt++)
#pragma unroll
      for (int r = 0; r < 4; r++) accO[nt][r] *= alpha[r];
    // P -> LDS (bf16)
#pragma unroll
    for (int nt = 0; nt < 4; nt++)
#pragma unroll
      for (int r = 0; r < 4; r++)
        Pw[(g*4 + r)*72 + nt*16 + r16] = f2bf(s[nt][r]);
    // O += P @ V
#pragma unroll
    for (int nt = 0; nt < 8; nt++){
      int dd = nt*16 + r16;
      int sv = (((dd & 7) ^ ((dd >> 3) & 7)) << 3);
#pragma unroll
      for (int kk2 = 0; kk2 < 2; kk2++){
        u16x8 pa = *reinterpret_cast<const u16x8*>((char*)Pw + r16*144 + kk2*64 + g*16);
        u16x8 vf = *reinterpret_cast<const u16x8*>(Vt + (size_t)dd*64 + ((kk2*32 + g*8) ^ sv));
        accO[nt] = mfma16(pa, vf, accO[nt]);
      }
    }
    __syncthreads();
  }
  float invl[4];
#pragma unroll
  for (int r = 0; r < 4; r++) invl[r] = 1.0f / lrow[r];
#pragma unroll
  for (int nt = 0; nt < 8; nt++){
#pragma unroll
    for (int r = 0; r < 4; r++){
      int token = q0 + g*4 + r;
      O[((size_t)(b*2048 + token))*2048 + h*128 + nt*16 + r16] = f2bf(accO[nt][r] * invl[r]);
    }
  }
}

// ---------------------------------------------------------------------------
extern "C" void kernel_launch(void* const* d_in, const int* in_sizes, int n_in,
                              void* d_out, int out_size, void* d_ws, size_t ws_size,
                              hipStream_t stream){
  (void)in_sizes; (void)n_in; (void)out_size; (void)ws_size;
  const float* hid   = (const float*)d_in[0];
  const float* temb  = (const float*)d_in[1];
  const float* w_ln  = (const float*)d_in[2];
  const float* w_mod = (const float*)d_in[3];
  const float* b_mod = (const float*)d_in[4];
  const float* wq    = (const float*)d_in[5];
  const float* wk    = (const float*)d_in[6];
  const float* wv    = (const float*)d_in[7];
  const float* wo    = (const float*)d_in[8];
  const float* qn_w  = (const float*)d_in[9];
  const float* kn_w  = (const float*)d_in[10];
  const float* cos1  = (const float*)d_in[11];
  const float* sin1  = (const float*)d_in[12];
  const float* rope3 = (const float*)d_in[13];
  const int*   mpos  = (const int*)d_in[14];
  float* out = (float*)d_out;

  // Workspace map (MB; non-overlapping for their live ranges):
  //   [0, 48K)      modb ; [128K, 896K) partb
  //   [1, 17)       xm   (16 MB; dead after gemm<0>; reused as ao)
  //   [17, 33)      wqkvT(16 MB; dead after gemm<0>; reused as Qn)
  //   [33, 41)      woT  (8 MB; live until gemm<1>)
  //   [41, 73)      qkv  (32 MB)
  //   [73, 81)      Kn ; [81, 89) Vn
  char* ws = (char*)d_ws;
  const size_t MB = 1u << 20;
  float* modb  = (float*)(ws + 0);
  float* partb = (float*)(ws + 131072);
  u16* xm    = (u16*)(ws + 1*MB);
  u16* wqkvT = (u16*)(ws + 17*MB);
  u16* woT   = (u16*)(ws + 33*MB);
  u16* qkv   = (u16*)(ws + 41*MB);
  u16* Qn    = (u16*)(ws + 17*MB);   // aliases wqkvT (dead by then)
  u16* Kn    = (u16*)(ws + 73*MB);
  u16* Vn    = (u16*)(ws + 81*MB);
  u16* ao    = (u16*)(ws + 1*MB);    // aliases xm (dead by then)

  // weights -> bf16, transposed (N-major)
  tcast_kernel<<<dim3(32,32), 256, 0, stream>>>(wq, wqkvT, 2048);
  tcast_kernel<<<dim3(16,32), 256, 0, stream>>>(wk, wqkvT + (size_t)2048*2048, 1024);
  tcast_kernel<<<dim3(16,32), 256, 0, stream>>>(wv, wqkvT + (size_t)3072*2048, 1024);
  tcast_kernel<<<dim3(32,32), 256, 0, stream>>>(wo, woT, 2048);
  // modulation
  mod_part_kernel<<<dim3(24,16), 256, 0, stream>>>(temb, w_mod, partb);
  mod_reduce_kernel<<<24, 256, 0, stream>>>(partb, b_mod, modb);
  // norm + modulate
  rmsmod_kernel<<<4096, 256, 0, stream>>>(hid, w_ln, modb, xm);
  // QKV projection
  gemm_kernel<0><<<dim3(32,32), 256, 0, stream>>>(xm, wqkvT, 4096, 4096, 2048,
                                                  qkv, nullptr, nullptr, nullptr);
  // qk-norm + rope + head split
  qknorm_rope_kernel<<<dim3(4096,8), 256, 0, stream>>>(qkv, qn_w, kn_w, cos1, sin1,
                                                       rope3, mpos, Qn, Kn, Vn);
  // attention
  attn_kernel<<<dim3(32,32), 256, 0, stream>>>(Qn, Kn, Vn, ao);
  // O-projection + residual + gate (fused)
  gemm_kernel<1><<<dim3(16,32), 256, 0, stream>>>(ao, woT, 4096, 2048, 2048,
                                                  nullptr, hid, modb, out);
}